// Round 3
// baseline (438.250 us; speedup 1.0000x reference)
//
#include <hip/hip_runtime.h>
#include <hip/hip_bf16.h>

// RNN_41807211659578 R3: register-pinned fp8 weights (waves_per_eu(2,2)),
// transposed MFMA (A=weights, B=activations) for packed writebacks,
// f32 LDS shadow for recurrent carry, 4 barriers/step, yb double-buffered.

typedef unsigned short u16;
typedef unsigned int u32;
typedef unsigned char u8;
typedef long i64;
typedef __attribute__((ext_vector_type(4))) float f32x4;

#define MFMA_F8(acc, a, b) (acc) = __builtin_amdgcn_mfma_f32_16x16x32_fp8_fp8((i64)(a), (i64)(b), (acc), 0, 0, 0)

__device__ __forceinline__ u8 f2e4(float v) {
  return (u8)(__builtin_amdgcn_cvt_pk_fp8_f32(v, 0.f, 0, false) & 0xff);
}
__device__ __forceinline__ float sigf(float x) {
  return __builtin_amdgcn_rcpf(1.f + __expf(-x));
}
__device__ __forceinline__ float tanh_fast(float x) {
  return 1.f - 2.f * __builtin_amdgcn_rcpf(1.f + __expf(2.f * x));
}

// ---- workspace layout: wsf floats at base; fp8 weight region at byte 16384 ----
constexpr int E0 = 2 * 384 * 352;      // W0cat [g][384][352] fp8
constexpr int E1 = E0 + 2 * 384 * 256; // W1cat [g][384][256]
constexpr int E2 = E1 + 2 * 128 * 128; // Wn0 (Whh0 n-rows)
constexpr int E3 = E2 + 2 * 128 * 128; // Wn1
constexpr int E4 = E3 + 2 * 128 * 128; // W1 (MLP)
constexpr int E5 = E4 + 2 * 128 * 128; // W2 (MLP)
constexpr int NBIAS = 2048;
constexpr int TOTAL = E5 + NBIAS + 4;
constexpr int WB_BYTE_OFF = 16384;

__global__ void prep_kernel(const float* __restrict__ Wih0, const float* __restrict__ Whh0,
                            const float* __restrict__ bih0, const float* __restrict__ bhh0,
                            const float* __restrict__ Wih1, const float* __restrict__ Whh1,
                            const float* __restrict__ bih1, const float* __restrict__ bhh1,
                            const float* __restrict__ W1, const float* __restrict__ W2,
                            u8* __restrict__ wb, float* __restrict__ wsf) {
  for (int idx = blockIdx.x * blockDim.x + threadIdx.x; idx < TOTAL;
       idx += gridDim.x * blockDim.x) {
    if (idx < E0) {
      int g = idx / 135168;
      int r = idx - g * 135168;
      int j = r / 352;
      int k = r - j * 352;
      const float* wi = Wih0 + (g * 384 + j) * 222;
      float v;
      if (k < 94) v = wi[k];
      else if (k < 96) v = 0.f;
      else if (k < 224) v = wi[k - 2];
      else v = Whh0[(g * 384 + j) * 128 + (k - 224)];
      wb[idx] = f2e4(v);
    } else if (idx < E1) {
      int q = idx - E0;
      int g = q / 98304;
      int r = q - g * 98304;
      int j = r >> 8;
      int k = r & 255;
      float v = (k < 128) ? Wih1[(g * 384 + j) * 128 + k]
                          : Whh1[(g * 384 + j) * 128 + (k - 128)];
      wb[idx] = f2e4(v);
    } else if (idx < E2) {
      int q = idx - E1; int g = q >> 14; int r = q & 16383; int j = r >> 7; int k = r & 127;
      wb[idx] = f2e4(Whh0[(g * 384 + 256 + j) * 128 + k]);
    } else if (idx < E3) {
      int q = idx - E2; int g = q >> 14; int r = q & 16383; int j = r >> 7; int k = r & 127;
      wb[idx] = f2e4(Whh1[(g * 384 + 256 + j) * 128 + k]);
    } else if (idx < E4) {
      int q = idx - E3; int g = q >> 14; int r = q & 16383; int j = r >> 7; int k = r & 127;
      wb[idx] = f2e4(W1[(g * 128 + j) * 128 + k]);
    } else if (idx < E5) {
      int q = idx - E4; int g = q >> 14; int r = q & 16383; int j = r >> 7; int k = r & 127;
      wb[idx] = f2e4(W2[(g * 128 + j) * 128 + k]);
    } else if (idx < E5 + NBIAS) {
      int q = idx - E5;
      float v;
      if (q < 512)       { int g = q >> 8, j = q & 255;              v = bih0[g*384 + j] + bhh0[g*384 + j]; }
      else if (q < 768)  { int p = q - 512;  int g = p >> 7, j = p & 127; v = bih0[g*384 + 256 + j]; }
      else if (q < 1024) { int p = q - 768;  int g = p >> 7, j = p & 127; v = bhh0[g*384 + 256 + j]; }
      else if (q < 1536) { int p = q - 1024; int g = p >> 8, j = p & 255; v = bih1[g*384 + j] + bhh1[g*384 + j]; }
      else if (q < 1792) { int p = q - 1536; int g = p >> 7, j = p & 127; v = bih1[g*384 + 256 + j]; }
      else               { int p = q - 1792; int g = p >> 7, j = p & 127; v = bhh1[g*384 + 256 + j]; }
      wsf[4 + q] = v;
    } else {
      wsf[idx - (E5 + NBIAS)] = 0.f;
    }
  }
}

__global__ __launch_bounds__(512) __attribute__((amdgpu_waves_per_eu(2, 2)))
void rnn_kernel(const float* __restrict__ states,
                const u8* __restrict__ wb,
                float* __restrict__ wsf,
                const float* __restrict__ b1g,
                const float* __restrict__ b2g,
                const float* __restrict__ Wmg,
                const float* __restrict__ bmg) {
  const int blk = blockIdx.x;
  const int g = (blk < 96) ? 0 : 1;
  const int r0 = (g == 0) ? (blk * 32) : ((blk - 96) * 32);
  const int aAg = (g == 0 ? 0 : 12) + (r0 >> 8);
  const int b0 = r0 & 255;

  const int tid = threadIdx.x;
  const int wid = tid >> 6;
  const int ln = tid & 63;
  const int j_in = ln & 15;
  const int kq = ln >> 4;
  const int c0 = wid * 16 + kq * 4; // first of the 4 hidden cols this lane owns in D

  __shared__ __align__(16) u8 h0b[32 * 136];
  __shared__ __align__(16) u8 h1b[32 * 136];
  __shared__ __align__(16) u8 d1b[32 * 136];
  __shared__ __align__(16) u8 d2b[32 * 136];
  __shared__ __align__(16) u8 yb[2][32 * 104];
  __shared__ __align__(16) float h0f[32 * 132];
  __shared__ __align__(16) float h1f[32 * 132];
  __shared__ __align__(16) float bias[1536]; // r0,z0,in0,hn0,r1,z1,in1,hn1,b1,b2,Wm[2][128]
  __shared__ float dmv[32][2];
  __shared__ float red[32][3];

  // ---- weights into registers (fp8, once) ----
  const u8* W0  = wb + g * 135168;
  const u8* W1c = wb + E0 + g * 98304;
  const u8* Wn0p = wb + E1 + g * 16384;
  const u8* Wn1p = wb + E2 + g * 16384;
  const u8* Wm1p = wb + E3 + g * 16384;
  const u8* Wm2p = wb + E4 + g * 16384;

  i64 w0r[11], w0z[11], w0n[11];
#pragma unroll
  for (int kt = 0; kt < 11; ++kt) {
    w0r[kt] = *(const i64*)(W0 + (j_in + wid * 16)       * 352 + kt * 32 + kq * 8);
    w0z[kt] = *(const i64*)(W0 + (128 + j_in + wid * 16) * 352 + kt * 32 + kq * 8);
    w0n[kt] = *(const i64*)(W0 + (256 + j_in + wid * 16) * 352 + kt * 32 + kq * 8);
  }
  i64 w1r[8], w1z[8], w1n[8];
#pragma unroll
  for (int kt = 0; kt < 8; ++kt) {
    w1r[kt] = *(const i64*)(W1c + (j_in + wid * 16)       * 256 + kt * 32 + kq * 8);
    w1z[kt] = *(const i64*)(W1c + (128 + j_in + wid * 16) * 256 + kt * 32 + kq * 8);
    w1n[kt] = *(const i64*)(W1c + (256 + j_in + wid * 16) * 256 + kt * 32 + kq * 8);
  }
  i64 wn0[4], wn1[4], wm1[4], wm2[4];
#pragma unroll
  for (int kt = 0; kt < 4; ++kt) {
    wn0[kt] = *(const i64*)(Wn0p + (j_in + wid * 16) * 128 + kt * 32 + kq * 8);
    wn1[kt] = *(const i64*)(Wn1p + (j_in + wid * 16) * 128 + kt * 32 + kq * 8);
    wm1[kt] = *(const i64*)(Wm1p + (j_in + wid * 16) * 128 + kt * 32 + kq * 8);
    wm2[kt] = *(const i64*)(Wm2p + (j_in + wid * 16) * 128 + kt * 32 + kq * 8);
  }

  // ---- biases + Wm into LDS ----
  for (int i = tid; i < 1536; i += 512) {
    float v;
    if (i < 256)       v = wsf[4 + g * 256 + i];
    else if (i < 384)  v = wsf[516 + g * 128 + (i - 256)];
    else if (i < 512)  v = wsf[772 + g * 128 + (i - 384)];
    else if (i < 768)  v = wsf[1028 + g * 256 + (i - 512)];
    else if (i < 896)  v = wsf[1540 + g * 128 + (i - 768)];
    else if (i < 1024) v = wsf[1796 + g * 128 + (i - 896)];
    else if (i < 1152) v = b1g[g * 128 + (i - 1024)];
    else if (i < 1280) v = b2g[g * 128 + (i - 1152)];
    else               v = Wmg[g * 256 + (i - 1280)];
    bias[i] = v;
  }
  for (int i = tid; i < 32 * 136; i += 512) { h0b[i] = 0; h1b[i] = 0; }
  for (int i = tid; i < 32 * 132; i += 512) { h0f[i] = 0.f; h1f[i] = 0.f; }
  // stage yb[0] for t=0
  for (int idx = tid; idx < 32 * 96; idx += 512) {
    int i = idx / 96, k = idx - i * 96;
    const float* srow = states + ((size_t)(b0 + i)) * 92;
    float v = (k < 2) ? srow[aAg * 4 + 2 + k] : (k < 94 ? srow[k - 2] : 0.f);
    yb[0][i * 104 + k] = f2e4(v);
  }
  const float bmc = bmg[g * 2 + ((tid >> 3) & 1)];
  __syncthreads();

  float accL = 0.f, accEp = 0.f, accEv = 0.f;

  for (int t = 0; t < 48; ++t) {
    const u8* ybc = yb[t & 1];
    u8* ybn = yb[(t + 1) & 1];

    // ---- P1: long-latency loads first ----
    float sx=0, sy=0, svx=0, svy=0, nx=0, ny=0, nvx=0, nvy=0;
    if (tid < 32) {
      const float* sr = states + ((size_t)(t * 256 + b0 + tid)) * 92 + aAg * 4;
      const float* sn = sr + 256 * 92;
      sx = sr[0]; sy = sr[1]; svx = sr[2]; svy = sr[3];
      nx = sn[0]; ny = sn[1]; nvx = sn[2]; nvy = sn[3];
    }
    float sv[6];
#pragma unroll
    for (int q = 0; q < 6; ++q) {
      int idx = tid + q * 512;
      int i = idx / 96, k = idx - i * 96;
      const float* srow = states + ((size_t)((t + 1) * 256 + b0 + i)) * 92;
      sv[q] = (k < 2) ? srow[aAg * 4 + 2 + k] : (k < 94 ? srow[k - 2] : 0.f);
    }

    // activation B-fragments (batch rows j_in and 16+j_in)
    i64 fy[3][2], fh1[4][2], fh0[4][2];
#pragma unroll
    for (int kt = 0; kt < 3; ++kt) {
      fy[kt][0] = *(const i64*)(ybc + j_in * 104 + kt * 32 + kq * 8);
      fy[kt][1] = *(const i64*)(ybc + (16 + j_in) * 104 + kt * 32 + kq * 8);
    }
#pragma unroll
    for (int kt = 0; kt < 4; ++kt) {
      fh1[kt][0] = *(const i64*)(h1b + j_in * 136 + kt * 32 + kq * 8);
      fh1[kt][1] = *(const i64*)(h1b + (16 + j_in) * 136 + kt * 32 + kq * 8);
      fh0[kt][0] = *(const i64*)(h0b + j_in * 136 + kt * 32 + kq * 8);
      fh0[kt][1] = *(const i64*)(h0b + (16 + j_in) * 136 + kt * 32 + kq * 8);
    }

    // MLP1: D^T = Wm1 x h1
    {
      f32x4 m0 = {0,0,0,0}, m1 = {0,0,0,0};
#pragma unroll
      for (int kt = 0; kt < 4; ++kt) {
        MFMA_F8(m0, wm1[kt], fh1[kt][0]);
        MFMA_F8(m1, wm1[kt], fh1[kt][1]);
      }
      f32x4 b1v = *(const f32x4*)(bias + 1024 + c0);
      u32 p = (u32)__builtin_amdgcn_cvt_pk_fp8_f32(fmaxf(m0[0]+b1v[0],0.f), fmaxf(m0[1]+b1v[1],0.f), 0, false);
      p = (u32)__builtin_amdgcn_cvt_pk_fp8_f32(fmaxf(m0[2]+b1v[2],0.f), fmaxf(m0[3]+b1v[3],0.f), (int)p, true);
      *(u32*)(d1b + j_in * 136 + c0) = p;
      p = (u32)__builtin_amdgcn_cvt_pk_fp8_f32(fmaxf(m1[0]+b1v[0],0.f), fmaxf(m1[1]+b1v[1],0.f), 0, false);
      p = (u32)__builtin_amdgcn_cvt_pk_fp8_f32(fmaxf(m1[2]+b1v[2],0.f), fmaxf(m1[3]+b1v[3],0.f), (int)p, true);
      *(u32*)(d1b + (16 + j_in) * 136 + c0) = p;
    }

    // GRU0: gates^T over K=[y(96)|h1(128)|h0(128)]
    f32x4 hv0[2];
    {
      f32x4 aR[2] = {{0,0,0,0},{0,0,0,0}};
      f32x4 aZ[2] = {{0,0,0,0},{0,0,0,0}};
      f32x4 aN[2] = {{0,0,0,0},{0,0,0,0}};
      f32x4 aG[2] = {{0,0,0,0},{0,0,0,0}};
#pragma unroll
      for (int kt = 0; kt < 11; ++kt) {
        i64 bb0 = (kt < 3) ? fy[kt][0] : (kt < 7 ? fh1[kt - 3][0] : fh0[kt - 7][0]);
        i64 bb1 = (kt < 3) ? fy[kt][1] : (kt < 7 ? fh1[kt - 3][1] : fh0[kt - 7][1]);
        MFMA_F8(aR[0], w0r[kt], bb0); MFMA_F8(aR[1], w0r[kt], bb1);
        MFMA_F8(aZ[0], w0z[kt], bb0); MFMA_F8(aZ[1], w0z[kt], bb1);
        MFMA_F8(aN[0], w0n[kt], bb0); MFMA_F8(aN[1], w0n[kt], bb1);
      }
#pragma unroll
      for (int kt = 0; kt < 4; ++kt) {
        MFMA_F8(aG[0], wn0[kt], fh0[kt][0]);
        MFMA_F8(aG[1], wn0[kt], fh0[kt][1]);
      }
      f32x4 brv = *(const f32x4*)(bias + c0);
      f32x4 bzv = *(const f32x4*)(bias + 128 + c0);
      f32x4 biv = *(const f32x4*)(bias + 256 + c0);
      f32x4 bhv = *(const f32x4*)(bias + 384 + c0);
      f32x4 hold0 = *(const f32x4*)(h0f + j_in * 132 + c0);
      f32x4 hold1 = *(const f32x4*)(h0f + (16 + j_in) * 132 + c0);
#pragma unroll
      for (int i = 0; i < 4; ++i) {
        float r0v = sigf(aR[0][i] + brv[i]);
        float z0v = sigf(aZ[0][i] + bzv[i]);
        float n0v = tanh_fast(aN[0][i] + biv[i] + (r0v - 1.f) * aG[0][i] + r0v * bhv[i]);
        hv0[0][i] = (1.f - z0v) * n0v + z0v * hold0[i];
        float r1v = sigf(aR[1][i] + brv[i]);
        float z1v = sigf(aZ[1][i] + bzv[i]);
        float n1v = tanh_fast(aN[1][i] + biv[i] + (r1v - 1.f) * aG[1][i] + r1v * bhv[i]);
        hv0[1][i] = (1.f - z1v) * n1v + z1v * hold1[i];
      }
    }
    __syncthreads(); // B1

    // ---- P2: h0 writeback (packed) + MLP2 ----
#pragma unroll
    for (int nt = 0; nt < 2; ++nt) {
      u32 p = (u32)__builtin_amdgcn_cvt_pk_fp8_f32(hv0[nt][0], hv0[nt][1], 0, false);
      p = (u32)__builtin_amdgcn_cvt_pk_fp8_f32(hv0[nt][2], hv0[nt][3], (int)p, true);
      *(u32*)(h0b + (nt * 16 + j_in) * 136 + c0) = p;
      *(f32x4*)(h0f + (nt * 16 + j_in) * 132 + c0) = hv0[nt];
    }
    {
      f32x4 n0 = {0,0,0,0}, n1 = {0,0,0,0};
#pragma unroll
      for (int kt = 0; kt < 4; ++kt) {
        i64 bb0 = *(const i64*)(d1b + j_in * 136 + kt * 32 + kq * 8);
        i64 bb1 = *(const i64*)(d1b + (16 + j_in) * 136 + kt * 32 + kq * 8);
        MFMA_F8(n0, wm2[kt], bb0);
        MFMA_F8(n1, wm2[kt], bb1);
      }
      f32x4 b2v = *(const f32x4*)(bias + 1152 + c0);
      u32 p = (u32)__builtin_amdgcn_cvt_pk_fp8_f32(fmaxf(n0[0]+b2v[0],0.f), fmaxf(n0[1]+b2v[1],0.f), 0, false);
      p = (u32)__builtin_amdgcn_cvt_pk_fp8_f32(fmaxf(n0[2]+b2v[2],0.f), fmaxf(n0[3]+b2v[3],0.f), (int)p, true);
      *(u32*)(d2b + j_in * 136 + c0) = p;
      p = (u32)__builtin_amdgcn_cvt_pk_fp8_f32(fmaxf(n1[0]+b2v[0],0.f), fmaxf(n1[1]+b2v[1],0.f), 0, false);
      p = (u32)__builtin_amdgcn_cvt_pk_fp8_f32(fmaxf(n1[2]+b2v[2],0.f), fmaxf(n1[3]+b2v[3],0.f), (int)p, true);
      *(u32*)(d2b + (16 + j_in) * 136 + c0) = p;
    }
    __syncthreads(); // B2

    // ---- P3: GRU1 + dm ----
    f32x4 hv1[2];
    {
      i64 g0f[4][2];
#pragma unroll
      for (int kt = 0; kt < 4; ++kt) {
        g0f[kt][0] = *(const i64*)(h0b + j_in * 136 + kt * 32 + kq * 8);
        g0f[kt][1] = *(const i64*)(h0b + (16 + j_in) * 136 + kt * 32 + kq * 8);
      }
      f32x4 aR[2] = {{0,0,0,0},{0,0,0,0}};
      f32x4 aZ[2] = {{0,0,0,0},{0,0,0,0}};
      f32x4 aN[2] = {{0,0,0,0},{0,0,0,0}};
      f32x4 aG[2] = {{0,0,0,0},{0,0,0,0}};
#pragma unroll
      for (int kt = 0; kt < 8; ++kt) {
        i64 bb0 = (kt < 4) ? g0f[kt][0] : fh1[kt - 4][0];
        i64 bb1 = (kt < 4) ? g0f[kt][1] : fh1[kt - 4][1];
        MFMA_F8(aR[0], w1r[kt], bb0); MFMA_F8(aR[1], w1r[kt], bb1);
        MFMA_F8(aZ[0], w1z[kt], bb0); MFMA_F8(aZ[1], w1z[kt], bb1);
        MFMA_F8(aN[0], w1n[kt], bb0); MFMA_F8(aN[1], w1n[kt], bb1);
      }
#pragma unroll
      for (int kt = 0; kt < 4; ++kt) {
        MFMA_F8(aG[0], wn1[kt], fh1[kt][0]);
        MFMA_F8(aG[1], wn1[kt], fh1[kt][1]);
      }
      // dm partials while MFMAs in flight
      {
        int row = tid >> 4, c = (tid >> 3) & 1, part = tid & 7;
        const u8* dp = d2b + row * 136 + part * 16;
        const float* wmr = bias + 1280 + c * 128 + part * 16;
        float s = 0.f;
#pragma unroll
        for (int q = 0; q < 4; ++q) {
          u32 w = *(const u32*)(dp + q * 4);
          s += wmr[q * 4 + 0] * __builtin_amdgcn_cvt_f32_fp8((int)w, 0);
          s += wmr[q * 4 + 1] * __builtin_amdgcn_cvt_f32_fp8((int)w, 1);
          s += wmr[q * 4 + 2] * __builtin_amdgcn_cvt_f32_fp8((int)w, 2);
          s += wmr[q * 4 + 3] * __builtin_amdgcn_cvt_f32_fp8((int)w, 3);
        }
        s += __shfl_xor(s, 1); s += __shfl_xor(s, 2); s += __shfl_xor(s, 4);
        if (part == 0) dmv[row][c] = s + bmc;
      }
      f32x4 brv = *(const f32x4*)(bias + 512 + c0);
      f32x4 bzv = *(const f32x4*)(bias + 640 + c0);
      f32x4 biv = *(const f32x4*)(bias + 768 + c0);
      f32x4 bhv = *(const f32x4*)(bias + 896 + c0);
      f32x4 hold0 = *(const f32x4*)(h1f + j_in * 132 + c0);
      f32x4 hold1 = *(const f32x4*)(h1f + (16 + j_in) * 132 + c0);
#pragma unroll
      for (int i = 0; i < 4; ++i) {
        float r0v = sigf(aR[0][i] + brv[i]);
        float z0v = sigf(aZ[0][i] + bzv[i]);
        float n0v = tanh_fast(aN[0][i] + biv[i] + (r0v - 1.f) * aG[0][i] + r0v * bhv[i]);
        hv1[0][i] = (1.f - z0v) * n0v + z0v * hold0[i];
        float r1v = sigf(aR[1][i] + brv[i]);
        float z1v = sigf(aZ[1][i] + bzv[i]);
        float n1v = tanh_fast(aN[1][i] + biv[i] + (r1v - 1.f) * aG[1][i] + r1v * bhv[i]);
        hv1[1][i] = (1.f - z1v) * n1v + z1v * hold1[i];
      }
    }
    __syncthreads(); // B3

    // ---- P4: h1 writeback + error + yb staging for t+1 ----
#pragma unroll
    for (int nt = 0; nt < 2; ++nt) {
      u32 p = (u32)__builtin_amdgcn_cvt_pk_fp8_f32(hv1[nt][0], hv1[nt][1], 0, false);
      p = (u32)__builtin_amdgcn_cvt_pk_fp8_f32(hv1[nt][2], hv1[nt][3], (int)p, true);
      *(u32*)(h1b + (nt * 16 + j_in) * 136 + c0) = p;
      *(f32x4*)(h1f + (nt * 16 + j_in) * 132 + c0) = hv1[nt];
    }
    if (tid < 32) {
      float dx = dmv[tid][0] - nvx;
      float dy = dmv[tid][1] - nvy;
      float e = sqrtf(dx * dx + dy * dy);
      accL += e;
      if (t >= 12) {
        accEv += e;
        float ex = sx + 0.1f * svx - nx;
        float ey = sy + 0.1f * svy - ny;
        accEp += sqrtf(ex * ex + ey * ey);
      }
    }
#pragma unroll
    for (int q = 0; q < 6; ++q) {
      int idx = tid + q * 512;
      int i = idx / 96, k = idx - i * 96;
      ybn[i * 104 + k] = f2e4(sv[q]);
    }
    __syncthreads(); // B4
  }

  if (tid < 32) { red[tid][0] = accL; red[tid][1] = accEp; red[tid][2] = accEv; }
  __syncthreads();
  if (tid < 3) {
    float s = 0.f;
    for (int i = 0; i < 32; ++i) s += red[i][tid];
    atomicAdd(&wsf[tid], s);
  }
}

__global__ void fin_kernel(const float* __restrict__ wacc, float* __restrict__ out) {
  if (threadIdx.x == 0 && blockIdx.x == 0) {
    out[0] = wacc[0] / 1104.f;
    out[1] = wacc[1] / 828.f;
    out[2] = wacc[2] / 828.f;
  }
}

extern "C" void kernel_launch(void* const* d_in, const int* in_sizes, int n_in,
                              void* d_out, int out_size, void* d_ws, size_t ws_size,
                              hipStream_t stream) {
  const float* states = (const float*)d_in[0];
  const float* Wih0 = (const float*)d_in[1];
  const float* Whh0 = (const float*)d_in[2];
  const float* bih0 = (const float*)d_in[3];
  const float* bhh0 = (const float*)d_in[4];
  const float* Wih1 = (const float*)d_in[5];
  const float* Whh1 = (const float*)d_in[6];
  const float* bih1 = (const float*)d_in[7];
  const float* bhh1 = (const float*)d_in[8];
  const float* W1   = (const float*)d_in[9];
  const float* b1   = (const float*)d_in[10];
  const float* W2   = (const float*)d_in[11];
  const float* b2   = (const float*)d_in[12];
  const float* Wm   = (const float*)d_in[13];
  const float* bm   = (const float*)d_in[14];

  float* wsf = (float*)d_ws;
  u8* wb = (u8*)d_ws + WB_BYTE_OFF;

  int prep_blocks = (TOTAL + 255) / 256;
  prep_kernel<<<prep_blocks, 256, 0, stream>>>(Wih0, Whh0, bih0, bhh0,
                                               Wih1, Whh1, bih1, bhh1,
                                               W1, W2, wb, wsf);
  rnn_kernel<<<184, 512, 0, stream>>>(states, wb, wsf, b1, b2, Wm, bm);
  fin_kernel<<<1, 64, 0, stream>>>(wsf, (float*)d_out);
}

// Round 4
// 361.070 us; speedup vs baseline: 1.2138x; 1.2138x over previous
//
#include <hip/hip_runtime.h>
#include <hip/hip_bf16.h>

// RNN_41807211659578 R4: transposed fp8 MFMA, register-resident weights (146 VGPR),
// f32 carry in registers (no shadow LDS), JIT LDS fragment loads, 3 barriers/step,
// error phase hoisted out of the loop (dmv history in LDS).

typedef unsigned short u16;
typedef unsigned int u32;
typedef unsigned char u8;
typedef long i64;
typedef __attribute__((ext_vector_type(4))) float f32x4;

#define MFMA_F8(acc, a, b) (acc) = __builtin_amdgcn_mfma_f32_16x16x32_fp8_fp8((i64)(a), (i64)(b), (acc), 0, 0, 0)

__device__ __forceinline__ u8 f2e4(float v) {
  return (u8)(__builtin_amdgcn_cvt_pk_fp8_f32(v, 0.f, 0, false) & 0xff);
}
__device__ __forceinline__ u32 pk4(float a, float b, float c, float d) {
  u32 p = (u32)__builtin_amdgcn_cvt_pk_fp8_f32(a, b, 0, false);
  return (u32)__builtin_amdgcn_cvt_pk_fp8_f32(c, d, (int)p, true);
}
__device__ __forceinline__ float sigf(float x) {
  return __builtin_amdgcn_rcpf(1.f + __expf(-x));
}
__device__ __forceinline__ float tanh_fast(float x) {
  return 1.f - 2.f * __builtin_amdgcn_rcpf(1.f + __expf(2.f * x));
}

// ---- workspace layout: wsf floats at base; fp8 weight region at byte 16384 ----
constexpr int E0 = 2 * 384 * 352;      // W0cat [g][384][352] fp8
constexpr int E1 = E0 + 2 * 384 * 256; // W1cat [g][384][256]
constexpr int E2 = E1 + 2 * 128 * 128; // Wn0 (Whh0 n-rows)
constexpr int E3 = E2 + 2 * 128 * 128; // Wn1
constexpr int E4 = E3 + 2 * 128 * 128; // W1 (MLP)
constexpr int E5 = E4 + 2 * 128 * 128; // W2 (MLP)
constexpr int NBIAS = 2048;
constexpr int TOTAL = E5 + NBIAS + 4;
constexpr int WB_BYTE_OFF = 16384;

__global__ void prep_kernel(const float* __restrict__ Wih0, const float* __restrict__ Whh0,
                            const float* __restrict__ bih0, const float* __restrict__ bhh0,
                            const float* __restrict__ Wih1, const float* __restrict__ Whh1,
                            const float* __restrict__ bih1, const float* __restrict__ bhh1,
                            const float* __restrict__ W1, const float* __restrict__ W2,
                            u8* __restrict__ wb, float* __restrict__ wsf) {
  for (int idx = blockIdx.x * blockDim.x + threadIdx.x; idx < TOTAL;
       idx += gridDim.x * blockDim.x) {
    if (idx < E0) {
      int g = idx / 135168;
      int r = idx - g * 135168;
      int j = r / 352;
      int k = r - j * 352;
      const float* wi = Wih0 + (g * 384 + j) * 222;
      float v;
      if (k < 94) v = wi[k];
      else if (k < 96) v = 0.f;
      else if (k < 224) v = wi[k - 2];
      else v = Whh0[(g * 384 + j) * 128 + (k - 224)];
      wb[idx] = f2e4(v);
    } else if (idx < E1) {
      int q = idx - E0;
      int g = q / 98304;
      int r = q - g * 98304;
      int j = r >> 8;
      int k = r & 255;
      float v = (k < 128) ? Wih1[(g * 384 + j) * 128 + k]
                          : Whh1[(g * 384 + j) * 128 + (k - 128)];
      wb[idx] = f2e4(v);
    } else if (idx < E2) {
      int q = idx - E1; int g = q >> 14; int r = q & 16383; int j = r >> 7; int k = r & 127;
      wb[idx] = f2e4(Whh0[(g * 384 + 256 + j) * 128 + k]);
    } else if (idx < E3) {
      int q = idx - E2; int g = q >> 14; int r = q & 16383; int j = r >> 7; int k = r & 127;
      wb[idx] = f2e4(Whh1[(g * 384 + 256 + j) * 128 + k]);
    } else if (idx < E4) {
      int q = idx - E3; int g = q >> 14; int r = q & 16383; int j = r >> 7; int k = r & 127;
      wb[idx] = f2e4(W1[(g * 128 + j) * 128 + k]);
    } else if (idx < E5) {
      int q = idx - E4; int g = q >> 14; int r = q & 16383; int j = r >> 7; int k = r & 127;
      wb[idx] = f2e4(W2[(g * 128 + j) * 128 + k]);
    } else if (idx < E5 + NBIAS) {
      int q = idx - E5;
      float v;
      if (q < 512)       { int g = q >> 8, j = q & 255;              v = bih0[g*384 + j] + bhh0[g*384 + j]; }
      else if (q < 768)  { int p = q - 512;  int g = p >> 7, j = p & 127; v = bih0[g*384 + 256 + j]; }
      else if (q < 1024) { int p = q - 768;  int g = p >> 7, j = p & 127; v = bhh0[g*384 + 256 + j]; }
      else if (q < 1536) { int p = q - 1024; int g = p >> 8, j = p & 255; v = bih1[g*384 + j] + bhh1[g*384 + j]; }
      else if (q < 1792) { int p = q - 1536; int g = p >> 7, j = p & 127; v = bih1[g*384 + 256 + j]; }
      else               { int p = q - 1792; int g = p >> 7, j = p & 127; v = bhh1[g*384 + 256 + j]; }
      wsf[4 + q] = v;
    } else {
      wsf[idx - (E5 + NBIAS)] = 0.f;
    }
  }
}

__global__ __launch_bounds__(512, 2) __attribute__((amdgpu_waves_per_eu(2, 2)))
void rnn_kernel(const float* __restrict__ states,
                const u8* __restrict__ wb,
                float* __restrict__ wsf,
                const float* __restrict__ b1g,
                const float* __restrict__ b2g,
                const float* __restrict__ Wmg,
                const float* __restrict__ bmg) {
  const int blk = blockIdx.x;
  const int g = (blk < 96) ? 0 : 1;
  const int r0 = (g == 0) ? (blk * 32) : ((blk - 96) * 32);
  const int aAg = (g == 0 ? 0 : 12) + (r0 >> 8);
  const int b0 = r0 & 255;

  const int tid = threadIdx.x;
  const int wid = tid >> 6;
  const int ln = tid & 63;
  const int j_in = ln & 15;
  const int kq = ln >> 4;
  const int c0 = wid * 16 + kq * 4; // 4 hidden cols owned by this lane in D

  __shared__ __align__(16) u8 h0b[2][32 * 136];
  __shared__ __align__(16) u8 h1b[2][32 * 136];
  __shared__ __align__(16) u8 yb[2][32 * 104];
  __shared__ __align__(16) u8 d1b[32 * 136];
  __shared__ __align__(16) u8 d2b[32 * 136];
  __shared__ __align__(16) float bias[1536]; // r0,z0,in0,hn0,r1,z1,in1,hn1,b1,b2,Wm[2][128]
  __shared__ float dmv[48][32][2];
  __shared__ float red[8][3];

  // ---- weights into registers (fp8, once) ----
  const u8* W0   = wb + g * 135168;
  const u8* W1c  = wb + E0 + g * 98304;
  const u8* Wn0p = wb + E1 + g * 16384;
  const u8* Wn1p = wb + E2 + g * 16384;
  const u8* Wm1p = wb + E3 + g * 16384;
  const u8* Wm2p = wb + E4 + g * 16384;
  const int jh = wid * 16 + j_in;

  i64 w0r[11], w0z[11], w0n[11];
#pragma unroll
  for (int kt = 0; kt < 11; ++kt) {
    w0r[kt] = *(const i64*)(W0 + (jh)       * 352 + kt * 32 + kq * 8);
    w0z[kt] = *(const i64*)(W0 + (128 + jh) * 352 + kt * 32 + kq * 8);
    w0n[kt] = *(const i64*)(W0 + (256 + jh) * 352 + kt * 32 + kq * 8);
  }
  i64 w1r[8], w1z[8], w1n[8];
#pragma unroll
  for (int kt = 0; kt < 8; ++kt) {
    w1r[kt] = *(const i64*)(W1c + (jh)       * 256 + kt * 32 + kq * 8);
    w1z[kt] = *(const i64*)(W1c + (128 + jh) * 256 + kt * 32 + kq * 8);
    w1n[kt] = *(const i64*)(W1c + (256 + jh) * 256 + kt * 32 + kq * 8);
  }
  i64 wn0[4], wn1[4], wm1[4], wm2[4];
#pragma unroll
  for (int kt = 0; kt < 4; ++kt) {
    wn0[kt] = *(const i64*)(Wn0p + jh * 128 + kt * 32 + kq * 8);
    wn1[kt] = *(const i64*)(Wn1p + jh * 128 + kt * 32 + kq * 8);
    wm1[kt] = *(const i64*)(Wm1p + jh * 128 + kt * 32 + kq * 8);
    wm2[kt] = *(const i64*)(Wm2p + jh * 128 + kt * 32 + kq * 8);
  }

  // ---- biases + Wm into LDS ----
  for (int i = tid; i < 1536; i += 512) {
    float v;
    if (i < 256)       v = wsf[4 + g * 256 + i];
    else if (i < 384)  v = wsf[516 + g * 128 + (i - 256)];
    else if (i < 512)  v = wsf[772 + g * 128 + (i - 384)];
    else if (i < 768)  v = wsf[1028 + g * 256 + (i - 512)];
    else if (i < 896)  v = wsf[1540 + g * 128 + (i - 768)];
    else if (i < 1024) v = wsf[1796 + g * 128 + (i - 896)];
    else if (i < 1152) v = b1g[g * 128 + (i - 1024)];
    else if (i < 1280) v = b2g[g * 128 + (i - 1152)];
    else               v = Wmg[g * 256 + (i - 1280)];
    bias[i] = v;
  }
  for (int i = tid; i < 32 * 136; i += 512) { h0b[0][i] = 0; h1b[0][i] = 0; }
  // stage yb[0] for t=0 (packed u32 writes)
  for (int idx = tid; idx < 768; idx += 512) {
    int i = idx / 24, k4 = idx - i * 24;
    const float* srow = states + ((size_t)(b0 + i)) * 92;
    float v0, v1, v2, v3;
    if (k4 == 0) { v0 = srow[aAg*4+2]; v1 = srow[aAg*4+3]; v2 = srow[0]; v3 = srow[1]; }
    else {
      int kk = k4 * 4 - 2;
      v0 = srow[kk]; v1 = srow[kk+1];
      v2 = (kk+2 < 92) ? srow[kk+2] : 0.f;
      v3 = (kk+3 < 92) ? srow[kk+3] : 0.f;
    }
    *(u32*)(&yb[0][i * 104 + k4 * 4]) = pk4(v0, v1, v2, v3);
  }

  f32x4 hv0[2] = {{0,0,0,0},{0,0,0,0}};
  f32x4 hv1[2] = {{0,0,0,0},{0,0,0,0}};
  __syncthreads();

  for (int t = 0; t < 48; ++t) {
    const int cur = t & 1, nxt = cur ^ 1;
    const u8* h0c = h0b[cur]; u8* h0n = h0b[nxt];
    const u8* h1c = h1b[cur]; u8* h1n = h1b[nxt];
    const u8* ybc = yb[cur];  u8* ybn = yb[nxt];

    // ---- P1: issue y(t+1) global loads (held to P3) ----
    float yst[2][4];
#pragma unroll
    for (int q = 0; q < 2; ++q) {
      int idx = tid + q * 512;
      if (idx < 768) {
        int i = idx / 24, k4 = idx - i * 24;
        const float* srow = states + ((size_t)((t + 1) * 256 + b0 + i)) * 92;
        if (k4 == 0) { yst[q][0]=srow[aAg*4+2]; yst[q][1]=srow[aAg*4+3]; yst[q][2]=srow[0]; yst[q][3]=srow[1]; }
        else {
          int kk = k4 * 4 - 2;
          yst[q][0] = srow[kk]; yst[q][1] = srow[kk+1];
          yst[q][2] = (kk+2 < 92) ? srow[kk+2] : 0.f;
          yst[q][3] = (kk+3 < 92) ? srow[kk+3] : 0.f;
        }
      }
    }

    const u8* pH1a = h1c + j_in * 136 + kq * 8;
    const u8* pH1b = h1c + (16 + j_in) * 136 + kq * 8;
    const u8* pH0a = h0c + j_in * 136 + kq * 8;
    const u8* pH0b = h0c + (16 + j_in) * 136 + kq * 8;
    const u8* pYa  = ybc + j_in * 104 + kq * 8;
    const u8* pYb  = ybc + (16 + j_in) * 104 + kq * 8;

    // MLP1: d1 = relu(Wm1 x h1 + b1)
    {
      f32x4 m0 = {0,0,0,0}, m1 = {0,0,0,0};
#pragma unroll
      for (int kt = 0; kt < 4; ++kt) {
        i64 bb0 = *(const i64*)(pH1a + kt * 32);
        i64 bb1 = *(const i64*)(pH1b + kt * 32);
        MFMA_F8(m0, wm1[kt], bb0);
        MFMA_F8(m1, wm1[kt], bb1);
      }
      f32x4 b1v = *(const f32x4*)(bias + 1024 + c0);
      *(u32*)(d1b + j_in * 136 + c0) =
        pk4(fmaxf(m0[0]+b1v[0],0.f), fmaxf(m0[1]+b1v[1],0.f), fmaxf(m0[2]+b1v[2],0.f), fmaxf(m0[3]+b1v[3],0.f));
      *(u32*)(d1b + (16 + j_in) * 136 + c0) =
        pk4(fmaxf(m1[0]+b1v[0],0.f), fmaxf(m1[1]+b1v[1],0.f), fmaxf(m1[2]+b1v[2],0.f), fmaxf(m1[3]+b1v[3],0.f));
    }

    // GRU0: gates over K=[y(96)|h1(128)|h0(128)], aG = h0 @ Whh0_n
    {
      f32x4 aR[2] = {{0,0,0,0},{0,0,0,0}};
      f32x4 aZ[2] = {{0,0,0,0},{0,0,0,0}};
      f32x4 aN[2] = {{0,0,0,0},{0,0,0,0}};
      f32x4 aG[2] = {{0,0,0,0},{0,0,0,0}};
#pragma unroll
      for (int kt = 0; kt < 11; ++kt) {
        i64 bb0, bb1;
        if (kt < 3)      { bb0 = *(const i64*)(pYa + kt * 32);        bb1 = *(const i64*)(pYb + kt * 32); }
        else if (kt < 7) { bb0 = *(const i64*)(pH1a + (kt - 3) * 32); bb1 = *(const i64*)(pH1b + (kt - 3) * 32); }
        else             { bb0 = *(const i64*)(pH0a + (kt - 7) * 32); bb1 = *(const i64*)(pH0b + (kt - 7) * 32); }
        MFMA_F8(aR[0], w0r[kt], bb0); MFMA_F8(aR[1], w0r[kt], bb1);
        MFMA_F8(aZ[0], w0z[kt], bb0); MFMA_F8(aZ[1], w0z[kt], bb1);
        MFMA_F8(aN[0], w0n[kt], bb0); MFMA_F8(aN[1], w0n[kt], bb1);
        if (kt >= 7) { MFMA_F8(aG[0], wn0[kt - 7], bb0); MFMA_F8(aG[1], wn0[kt - 7], bb1); }
      }
      f32x4 brv = *(const f32x4*)(bias + c0);
      f32x4 bzv = *(const f32x4*)(bias + 128 + c0);
      f32x4 biv = *(const f32x4*)(bias + 256 + c0);
      f32x4 bhv = *(const f32x4*)(bias + 384 + c0);
#pragma unroll
      for (int nt = 0; nt < 2; ++nt)
#pragma unroll
        for (int i = 0; i < 4; ++i) {
          float rv = sigf(aR[nt][i] + brv[i]);
          float zv = sigf(aZ[nt][i] + bzv[i]);
          float nv = tanh_fast(aN[nt][i] + biv[i] + (rv - 1.f) * aG[nt][i] + rv * bhv[i]);
          hv0[nt][i] = (1.f - zv) * nv + zv * hv0[nt][i];
        }
    }
    __syncthreads(); // B1: d1b ready

    // ---- P2: h0 writeback + MLP2 ----
#pragma unroll
    for (int nt = 0; nt < 2; ++nt)
      *(u32*)(h0n + (nt * 16 + j_in) * 136 + c0) = pk4(hv0[nt][0], hv0[nt][1], hv0[nt][2], hv0[nt][3]);
    {
      f32x4 m0 = {0,0,0,0}, m1 = {0,0,0,0};
#pragma unroll
      for (int kt = 0; kt < 4; ++kt) {
        i64 bb0 = *(const i64*)(d1b + j_in * 136 + kt * 32 + kq * 8);
        i64 bb1 = *(const i64*)(d1b + (16 + j_in) * 136 + kt * 32 + kq * 8);
        MFMA_F8(m0, wm2[kt], bb0);
        MFMA_F8(m1, wm2[kt], bb1);
      }
      f32x4 b2v = *(const f32x4*)(bias + 1152 + c0);
      *(u32*)(d2b + j_in * 136 + c0) =
        pk4(fmaxf(m0[0]+b2v[0],0.f), fmaxf(m0[1]+b2v[1],0.f), fmaxf(m0[2]+b2v[2],0.f), fmaxf(m0[3]+b2v[3],0.f));
      *(u32*)(d2b + (16 + j_in) * 136 + c0) =
        pk4(fmaxf(m1[0]+b2v[0],0.f), fmaxf(m1[1]+b2v[1],0.f), fmaxf(m1[2]+b2v[2],0.f), fmaxf(m1[3]+b2v[3],0.f));
    }
    __syncthreads(); // B2: h0 new + d2b ready

    // ---- P3: GRU1 + dm + yb staging ----
    {
      f32x4 aR[2] = {{0,0,0,0},{0,0,0,0}};
      f32x4 aZ[2] = {{0,0,0,0},{0,0,0,0}};
      f32x4 aN[2] = {{0,0,0,0},{0,0,0,0}};
      f32x4 aG[2] = {{0,0,0,0},{0,0,0,0}};
      const u8* pG0a = h0n + j_in * 136 + kq * 8;
      const u8* pG0b = h0n + (16 + j_in) * 136 + kq * 8;
#pragma unroll
      for (int kt = 0; kt < 8; ++kt) {
        i64 bb0, bb1;
        if (kt < 4) { bb0 = *(const i64*)(pG0a + kt * 32);        bb1 = *(const i64*)(pG0b + kt * 32); }
        else        { bb0 = *(const i64*)(pH1a + (kt - 4) * 32);  bb1 = *(const i64*)(pH1b + (kt - 4) * 32); }
        MFMA_F8(aR[0], w1r[kt], bb0); MFMA_F8(aR[1], w1r[kt], bb1);
        MFMA_F8(aZ[0], w1z[kt], bb0); MFMA_F8(aZ[1], w1z[kt], bb1);
        MFMA_F8(aN[0], w1n[kt], bb0); MFMA_F8(aN[1], w1n[kt], bb1);
        if (kt >= 4) { MFMA_F8(aG[0], wn1[kt - 4], bb0); MFMA_F8(aG[1], wn1[kt - 4], bb1); }
      }
      // dm partials (reads d2b) while GRU1 MFMAs drain
      {
        int row = tid >> 4, c = (tid >> 3) & 1, part = tid & 7;
        const u8* dp = d2b + row * 136 + part * 16;
        const float* wmr = bias + 1280 + c * 128 + part * 16;
        float s = 0.f;
#pragma unroll
        for (int q = 0; q < 4; ++q) {
          u32 w = *(const u32*)(dp + q * 4);
          s += wmr[q * 4 + 0] * __builtin_amdgcn_cvt_f32_fp8((int)w, 0);
          s += wmr[q * 4 + 1] * __builtin_amdgcn_cvt_f32_fp8((int)w, 1);
          s += wmr[q * 4 + 2] * __builtin_amdgcn_cvt_f32_fp8((int)w, 2);
          s += wmr[q * 4 + 3] * __builtin_amdgcn_cvt_f32_fp8((int)w, 3);
        }
        s += __shfl_xor(s, 1); s += __shfl_xor(s, 2); s += __shfl_xor(s, 4);
        if (part == 0) dmv[t][row][c] = s;
      }
      f32x4 brv = *(const f32x4*)(bias + 512 + c0);
      f32x4 bzv = *(const f32x4*)(bias + 640 + c0);
      f32x4 biv = *(const f32x4*)(bias + 768 + c0);
      f32x4 bhv = *(const f32x4*)(bias + 896 + c0);
#pragma unroll
      for (int nt = 0; nt < 2; ++nt)
#pragma unroll
        for (int i = 0; i < 4; ++i) {
          float rv = sigf(aR[nt][i] + brv[i]);
          float zv = sigf(aZ[nt][i] + bzv[i]);
          float nv = tanh_fast(aN[nt][i] + biv[i] + (rv - 1.f) * aG[nt][i] + rv * bhv[i]);
          hv1[nt][i] = (1.f - zv) * nv + zv * hv1[nt][i];
        }
#pragma unroll
      for (int nt = 0; nt < 2; ++nt)
        *(u32*)(h1n + (nt * 16 + j_in) * 136 + c0) = pk4(hv1[nt][0], hv1[nt][1], hv1[nt][2], hv1[nt][3]);
    }
    // yb staging for t+1
#pragma unroll
    for (int q = 0; q < 2; ++q) {
      int idx = tid + q * 512;
      if (idx < 768) {
        int i = idx / 24, k4 = idx - i * 24;
        *(u32*)(ybn + i * 104 + k4 * 4) = pk4(yst[q][0], yst[q][1], yst[q][2], yst[q][3]);
      }
    }
    __syncthreads(); // B3: all t+1 state ready
  }

  // ---- error phase (post-loop, fully parallel) ----
  float accL = 0.f, accEp = 0.f, accEv = 0.f;
  const float bm0 = bmg[g * 2], bm1 = bmg[g * 2 + 1];
  for (int idx = tid; idx < 1536; idx += 512) {
    int t = idx >> 5, row = idx & 31;
    const float* sr = states + ((size_t)(t * 256 + b0 + row)) * 92 + aAg * 4;
    const float* sn = sr + 256 * 92;
    float dx = dmv[t][row][0] + bm0 - sn[2];
    float dy = dmv[t][row][1] + bm1 - sn[3];
    float e = sqrtf(dx * dx + dy * dy);
    accL += e;
    if (t >= 12) {
      accEv += e;
      float ex = sr[0] + 0.1f * sr[2] - sn[0];
      float ey = sr[1] + 0.1f * sr[3] - sn[1];
      accEp += sqrtf(ex * ex + ey * ey);
    }
  }
#pragma unroll
  for (int k = 1; k < 64; k <<= 1) {
    accL  += __shfl_xor(accL, k);
    accEp += __shfl_xor(accEp, k);
    accEv += __shfl_xor(accEv, k);
  }
  if (ln == 0) { red[wid][0] = accL; red[wid][1] = accEp; red[wid][2] = accEv; }
  __syncthreads();
  if (tid < 3) {
    float s = 0.f;
    for (int i = 0; i < 8; ++i) s += red[i][tid];
    atomicAdd(&wsf[tid], s);
  }
}

__global__ void fin_kernel(const float* __restrict__ wacc, float* __restrict__ out) {
  if (threadIdx.x == 0 && blockIdx.x == 0) {
    out[0] = wacc[0] / 1104.f;
    out[1] = wacc[1] / 828.f;
    out[2] = wacc[2] / 828.f;
  }
}

extern "C" void kernel_launch(void* const* d_in, const int* in_sizes, int n_in,
                              void* d_out, int out_size, void* d_ws, size_t ws_size,
                              hipStream_t stream) {
  const float* states = (const float*)d_in[0];
  const float* Wih0 = (const float*)d_in[1];
  const float* Whh0 = (const float*)d_in[2];
  const float* bih0 = (const float*)d_in[3];
  const float* bhh0 = (const float*)d_in[4];
  const float* Wih1 = (const float*)d_in[5];
  const float* Whh1 = (const float*)d_in[6];
  const float* bih1 = (const float*)d_in[7];
  const float* bhh1 = (const float*)d_in[8];
  const float* W1   = (const float*)d_in[9];
  const float* b1   = (const float*)d_in[10];
  const float* W2   = (const float*)d_in[11];
  const float* b2   = (const float*)d_in[12];
  const float* Wm   = (const float*)d_in[13];
  const float* bm   = (const float*)d_in[14];

  float* wsf = (float*)d_ws;
  u8* wb = (u8*)d_ws + WB_BYTE_OFF;

  int prep_blocks = (TOTAL + 255) / 256;
  prep_kernel<<<prep_blocks, 256, 0, stream>>>(Wih0, Whh0, bih0, bhh0,
                                               Wih1, Whh1, bih1, bhh1,
                                               W1, W2, wb, wsf);
  rnn_kernel<<<184, 512, 0, stream>>>(states, wb, wsf, b1, b2, Wm, bm);
  fin_kernel<<<1, 64, 0, stream>>>(wsf, (float*)d_out);
}

// Round 5
// 321.814 us; speedup vs baseline: 1.3618x; 1.1220x over previous
//
#include <hip/hip_runtime.h>
#include <hip/hip_bf16.h>

// RNN_41807211659578 R5: R4 + n-gate weight dedup (130 regs, 130 MFMA/wave/step)
// + asm-pinned register weights (defeat remat-from-L2 each step).

typedef unsigned short u16;
typedef unsigned int u32;
typedef unsigned char u8;
typedef long i64;
typedef __attribute__((ext_vector_type(4))) float f32x4;

#define MFMA_F8(acc, a, b) (acc) = __builtin_amdgcn_mfma_f32_16x16x32_fp8_fp8((i64)(a), (i64)(b), (acc), 0, 0, 0)

__device__ __forceinline__ void pin(i64& x) { asm volatile("" : "+v"(x)); }

__device__ __forceinline__ u8 f2e4(float v) {
  return (u8)(__builtin_amdgcn_cvt_pk_fp8_f32(v, 0.f, 0, false) & 0xff);
}
__device__ __forceinline__ u32 pk4(float a, float b, float c, float d) {
  u32 p = (u32)__builtin_amdgcn_cvt_pk_fp8_f32(a, b, 0, false);
  return (u32)__builtin_amdgcn_cvt_pk_fp8_f32(c, d, (int)p, true);
}
__device__ __forceinline__ float sigf(float x) {
  return __builtin_amdgcn_rcpf(1.f + __expf(-x));
}
__device__ __forceinline__ float tanh_fast(float x) {
  return 1.f - 2.f * __builtin_amdgcn_rcpf(1.f + __expf(2.f * x));
}

// ---- workspace layout: wsf floats at base; fp8 weight region at byte 16384 ----
constexpr int E0 = 2 * 384 * 352;      // W0cat [g][384][352] fp8
constexpr int E1 = E0 + 2 * 384 * 256; // W1cat [g][384][256]
constexpr int E2 = E1 + 2 * 128 * 128; // Wn0 (Whh0 n-rows)
constexpr int E3 = E2 + 2 * 128 * 128; // Wn1
constexpr int E4 = E3 + 2 * 128 * 128; // W1 (MLP)
constexpr int E5 = E4 + 2 * 128 * 128; // W2 (MLP)
constexpr int NBIAS = 2048;
constexpr int TOTAL = E5 + NBIAS + 4;
constexpr int WB_BYTE_OFF = 16384;

__global__ void prep_kernel(const float* __restrict__ Wih0, const float* __restrict__ Whh0,
                            const float* __restrict__ bih0, const float* __restrict__ bhh0,
                            const float* __restrict__ Wih1, const float* __restrict__ Whh1,
                            const float* __restrict__ bih1, const float* __restrict__ bhh1,
                            const float* __restrict__ W1, const float* __restrict__ W2,
                            u8* __restrict__ wb, float* __restrict__ wsf) {
  for (int idx = blockIdx.x * blockDim.x + threadIdx.x; idx < TOTAL;
       idx += gridDim.x * blockDim.x) {
    if (idx < E0) {
      int g = idx / 135168;
      int r = idx - g * 135168;
      int j = r / 352;
      int k = r - j * 352;
      const float* wi = Wih0 + (g * 384 + j) * 222;
      float v;
      if (k < 94) v = wi[k];
      else if (k < 96) v = 0.f;
      else if (k < 224) v = wi[k - 2];
      else v = Whh0[(g * 384 + j) * 128 + (k - 224)];
      wb[idx] = f2e4(v);
    } else if (idx < E1) {
      int q = idx - E0;
      int g = q / 98304;
      int r = q - g * 98304;
      int j = r >> 8;
      int k = r & 255;
      float v = (k < 128) ? Wih1[(g * 384 + j) * 128 + k]
                          : Whh1[(g * 384 + j) * 128 + (k - 128)];
      wb[idx] = f2e4(v);
    } else if (idx < E2) {
      int q = idx - E1; int g = q >> 14; int r = q & 16383; int j = r >> 7; int k = r & 127;
      wb[idx] = f2e4(Whh0[(g * 384 + 256 + j) * 128 + k]);
    } else if (idx < E3) {
      int q = idx - E2; int g = q >> 14; int r = q & 16383; int j = r >> 7; int k = r & 127;
      wb[idx] = f2e4(Whh1[(g * 384 + 256 + j) * 128 + k]);
    } else if (idx < E4) {
      int q = idx - E3; int g = q >> 14; int r = q & 16383; int j = r >> 7; int k = r & 127;
      wb[idx] = f2e4(W1[(g * 128 + j) * 128 + k]);
    } else if (idx < E5) {
      int q = idx - E4; int g = q >> 14; int r = q & 16383; int j = r >> 7; int k = r & 127;
      wb[idx] = f2e4(W2[(g * 128 + j) * 128 + k]);
    } else if (idx < E5 + NBIAS) {
      int q = idx - E5;
      float v;
      if (q < 512)       { int g = q >> 8, j = q & 255;              v = bih0[g*384 + j] + bhh0[g*384 + j]; }
      else if (q < 768)  { int p = q - 512;  int g = p >> 7, j = p & 127; v = bih0[g*384 + 256 + j]; }
      else if (q < 1024) { int p = q - 768;  int g = p >> 7, j = p & 127; v = bhh0[g*384 + 256 + j]; }
      else if (q < 1536) { int p = q - 1024; int g = p >> 8, j = p & 255; v = bih1[g*384 + j] + bhh1[g*384 + j]; }
      else if (q < 1792) { int p = q - 1536; int g = p >> 7, j = p & 127; v = bih1[g*384 + 256 + j]; }
      else               { int p = q - 1792; int g = p >> 7, j = p & 127; v = bhh1[g*384 + 256 + j]; }
      wsf[4 + q] = v;
    } else {
      wsf[idx - (E5 + NBIAS)] = 0.f;
    }
  }
}

__global__ __launch_bounds__(512, 2) __attribute__((amdgpu_waves_per_eu(2, 2)))
void rnn_kernel(const float* __restrict__ states,
                const u8* __restrict__ wb,
                float* __restrict__ wsf,
                const float* __restrict__ b1g,
                const float* __restrict__ b2g,
                const float* __restrict__ Wmg,
                const float* __restrict__ bmg) {
  const int blk = blockIdx.x;
  const int g = (blk < 96) ? 0 : 1;
  const int r0 = (g == 0) ? (blk * 32) : ((blk - 96) * 32);
  const int aAg = (g == 0 ? 0 : 12) + (r0 >> 8);
  const int b0 = r0 & 255;

  const int tid = threadIdx.x;
  const int wid = tid >> 6;
  const int ln = tid & 63;
  const int j_in = ln & 15;
  const int kq = ln >> 4;
  const int c0 = wid * 16 + kq * 4; // 4 hidden cols owned by this lane in D

  __shared__ __align__(16) u8 h0b[2][32 * 136];
  __shared__ __align__(16) u8 h1b[2][32 * 136];
  __shared__ __align__(16) u8 yb[2][32 * 104];
  __shared__ __align__(16) u8 d1b[32 * 136];
  __shared__ __align__(16) u8 d2b[32 * 136];
  __shared__ __align__(16) float bias[1536];
  __shared__ float dmv[48][32][2];
  __shared__ float red[8][3];

  // ---- weights into registers (fp8, once, asm-pinned vs remat) ----
  const u8* W0   = wb + g * 135168;
  const u8* W1c  = wb + E0 + g * 98304;
  const u8* Wn0p = wb + E1 + g * 16384;
  const u8* Wn1p = wb + E2 + g * 16384;
  const u8* Wm1p = wb + E3 + g * 16384;
  const u8* Wm2p = wb + E4 + g * 16384;
  const int jh = wid * 16 + j_in;

  i64 w0r[11], w0z[11], w0n[7];
#pragma unroll
  for (int kt = 0; kt < 11; ++kt) {
    w0r[kt] = *(const i64*)(W0 + (jh)       * 352 + kt * 32 + kq * 8);
    w0z[kt] = *(const i64*)(W0 + (128 + jh) * 352 + kt * 32 + kq * 8);
    if (kt < 7) w0n[kt] = *(const i64*)(W0 + (256 + jh) * 352 + kt * 32 + kq * 8);
  }
  i64 w1r[8], w1z[8], w1n[4];
#pragma unroll
  for (int kt = 0; kt < 8; ++kt) {
    w1r[kt] = *(const i64*)(W1c + (jh)       * 256 + kt * 32 + kq * 8);
    w1z[kt] = *(const i64*)(W1c + (128 + jh) * 256 + kt * 32 + kq * 8);
    if (kt < 4) w1n[kt] = *(const i64*)(W1c + (256 + jh) * 256 + kt * 32 + kq * 8);
  }
  i64 wn0[4], wn1[4], wm1[4], wm2[4];
#pragma unroll
  for (int kt = 0; kt < 4; ++kt) {
    wn0[kt] = *(const i64*)(Wn0p + jh * 128 + kt * 32 + kq * 8);
    wn1[kt] = *(const i64*)(Wn1p + jh * 128 + kt * 32 + kq * 8);
    wm1[kt] = *(const i64*)(Wm1p + jh * 128 + kt * 32 + kq * 8);
    wm2[kt] = *(const i64*)(Wm2p + jh * 128 + kt * 32 + kq * 8);
  }
  // opaque defs: values can no longer be rematerialized from memory
#pragma unroll
  for (int kt = 0; kt < 11; ++kt) { pin(w0r[kt]); pin(w0z[kt]); }
#pragma unroll
  for (int kt = 0; kt < 7; ++kt) pin(w0n[kt]);
#pragma unroll
  for (int kt = 0; kt < 8; ++kt) { pin(w1r[kt]); pin(w1z[kt]); }
#pragma unroll
  for (int kt = 0; kt < 4; ++kt) {
    pin(w1n[kt]); pin(wn0[kt]); pin(wn1[kt]); pin(wm1[kt]); pin(wm2[kt]);
  }

  // ---- biases + Wm into LDS ----
  for (int i = tid; i < 1536; i += 512) {
    float v;
    if (i < 256)       v = wsf[4 + g * 256 + i];
    else if (i < 384)  v = wsf[516 + g * 128 + (i - 256)];
    else if (i < 512)  v = wsf[772 + g * 128 + (i - 384)];
    else if (i < 768)  v = wsf[1028 + g * 256 + (i - 512)];
    else if (i < 896)  v = wsf[1540 + g * 128 + (i - 768)];
    else if (i < 1024) v = wsf[1796 + g * 128 + (i - 896)];
    else if (i < 1152) v = b1g[g * 128 + (i - 1024)];
    else if (i < 1280) v = b2g[g * 128 + (i - 1152)];
    else               v = Wmg[g * 256 + (i - 1280)];
    bias[i] = v;
  }
  for (int i = tid; i < 32 * 136; i += 512) { h0b[0][i] = 0; h1b[0][i] = 0; }
  for (int idx = tid; idx < 768; idx += 512) {
    int i = idx / 24, k4 = idx - i * 24;
    const float* srow = states + ((size_t)(b0 + i)) * 92;
    float v0, v1, v2, v3;
    if (k4 == 0) { v0 = srow[aAg*4+2]; v1 = srow[aAg*4+3]; v2 = srow[0]; v3 = srow[1]; }
    else {
      int kk = k4 * 4 - 2;
      v0 = srow[kk]; v1 = srow[kk+1];
      v2 = (kk+2 < 92) ? srow[kk+2] : 0.f;
      v3 = (kk+3 < 92) ? srow[kk+3] : 0.f;
    }
    *(u32*)(&yb[0][i * 104 + k4 * 4]) = pk4(v0, v1, v2, v3);
  }

  f32x4 hv0[2] = {{0,0,0,0},{0,0,0,0}};
  f32x4 hv1[2] = {{0,0,0,0},{0,0,0,0}};
  __syncthreads();

  for (int t = 0; t < 48; ++t) {
    const int cur = t & 1, nxt = cur ^ 1;
    const u8* h0c = h0b[cur]; u8* h0n = h0b[nxt];
    const u8* h1c = h1b[cur]; u8* h1n = h1b[nxt];
    const u8* ybc = yb[cur];  u8* ybn = yb[nxt];

    // ---- P1: y(t+1) prefetch ----
    float yst[2][4];
#pragma unroll
    for (int q = 0; q < 2; ++q) {
      int idx = tid + q * 512;
      if (idx < 768) {
        int i = idx / 24, k4 = idx - i * 24;
        const float* srow = states + ((size_t)((t + 1) * 256 + b0 + i)) * 92;
        if (k4 == 0) { yst[q][0]=srow[aAg*4+2]; yst[q][1]=srow[aAg*4+3]; yst[q][2]=srow[0]; yst[q][3]=srow[1]; }
        else {
          int kk = k4 * 4 - 2;
          yst[q][0] = srow[kk]; yst[q][1] = srow[kk+1];
          yst[q][2] = (kk+2 < 92) ? srow[kk+2] : 0.f;
          yst[q][3] = (kk+3 < 92) ? srow[kk+3] : 0.f;
        }
      }
    }

    const u8* pH1a = h1c + j_in * 136 + kq * 8;
    const u8* pH1b = h1c + (16 + j_in) * 136 + kq * 8;
    const u8* pH0a = h0c + j_in * 136 + kq * 8;
    const u8* pH0b = h0c + (16 + j_in) * 136 + kq * 8;
    const u8* pYa  = ybc + j_in * 104 + kq * 8;
    const u8* pYb  = ybc + (16 + j_in) * 104 + kq * 8;

    // MLP1: d1 = relu(Wm1 x h1 + b1)
    {
      f32x4 m0 = {0,0,0,0}, m1 = {0,0,0,0};
#pragma unroll
      for (int kt = 0; kt < 4; ++kt) {
        i64 bb0 = *(const i64*)(pH1a + kt * 32);
        i64 bb1 = *(const i64*)(pH1b + kt * 32);
        MFMA_F8(m0, wm1[kt], bb0);
        MFMA_F8(m1, wm1[kt], bb1);
      }
      f32x4 b1v = *(const f32x4*)(bias + 1024 + c0);
      *(u32*)(d1b + j_in * 136 + c0) =
        pk4(fmaxf(m0[0]+b1v[0],0.f), fmaxf(m0[1]+b1v[1],0.f), fmaxf(m0[2]+b1v[2],0.f), fmaxf(m0[3]+b1v[3],0.f));
      *(u32*)(d1b + (16 + j_in) * 136 + c0) =
        pk4(fmaxf(m1[0]+b1v[0],0.f), fmaxf(m1[1]+b1v[1],0.f), fmaxf(m1[2]+b1v[2],0.f), fmaxf(m1[3]+b1v[3],0.f));
    }

    // GRU0: r,z over K=[y|h1|h0]; aN = gi_n (y|h1), aG = gh_n (h0)
    {
      f32x4 aR[2] = {{0,0,0,0},{0,0,0,0}};
      f32x4 aZ[2] = {{0,0,0,0},{0,0,0,0}};
      f32x4 aN[2] = {{0,0,0,0},{0,0,0,0}};
      f32x4 aG[2] = {{0,0,0,0},{0,0,0,0}};
#pragma unroll
      for (int kt = 0; kt < 11; ++kt) {
        i64 bb0, bb1;
        if (kt < 3)      { bb0 = *(const i64*)(pYa + kt * 32);        bb1 = *(const i64*)(pYb + kt * 32); }
        else if (kt < 7) { bb0 = *(const i64*)(pH1a + (kt - 3) * 32); bb1 = *(const i64*)(pH1b + (kt - 3) * 32); }
        else             { bb0 = *(const i64*)(pH0a + (kt - 7) * 32); bb1 = *(const i64*)(pH0b + (kt - 7) * 32); }
        MFMA_F8(aR[0], w0r[kt], bb0); MFMA_F8(aR[1], w0r[kt], bb1);
        MFMA_F8(aZ[0], w0z[kt], bb0); MFMA_F8(aZ[1], w0z[kt], bb1);
        if (kt < 7) { MFMA_F8(aN[0], w0n[kt], bb0); MFMA_F8(aN[1], w0n[kt], bb1); }
        else        { MFMA_F8(aG[0], wn0[kt - 7], bb0); MFMA_F8(aG[1], wn0[kt - 7], bb1); }
      }
      f32x4 brv = *(const f32x4*)(bias + c0);
      f32x4 bzv = *(const f32x4*)(bias + 128 + c0);
      f32x4 biv = *(const f32x4*)(bias + 256 + c0);
      f32x4 bhv = *(const f32x4*)(bias + 384 + c0);
#pragma unroll
      for (int nt = 0; nt < 2; ++nt)
#pragma unroll
        for (int i = 0; i < 4; ++i) {
          float rv = sigf(aR[nt][i] + brv[i]);
          float zv = sigf(aZ[nt][i] + bzv[i]);
          float nv = tanh_fast(aN[nt][i] + biv[i] + rv * (aG[nt][i] + bhv[i]));
          hv0[nt][i] = (1.f - zv) * nv + zv * hv0[nt][i];
        }
    }
    __syncthreads(); // B1: d1b ready

    // ---- P2: h0 writeback + MLP2 ----
#pragma unroll
    for (int nt = 0; nt < 2; ++nt)
      *(u32*)(h0n + (nt * 16 + j_in) * 136 + c0) = pk4(hv0[nt][0], hv0[nt][1], hv0[nt][2], hv0[nt][3]);
    {
      f32x4 m0 = {0,0,0,0}, m1 = {0,0,0,0};
#pragma unroll
      for (int kt = 0; kt < 4; ++kt) {
        i64 bb0 = *(const i64*)(d1b + j_in * 136 + kt * 32 + kq * 8);
        i64 bb1 = *(const i64*)(d1b + (16 + j_in) * 136 + kt * 32 + kq * 8);
        MFMA_F8(m0, wm2[kt], bb0);
        MFMA_F8(m1, wm2[kt], bb1);
      }
      f32x4 b2v = *(const f32x4*)(bias + 1152 + c0);
      *(u32*)(d2b + j_in * 136 + c0) =
        pk4(fmaxf(m0[0]+b2v[0],0.f), fmaxf(m0[1]+b2v[1],0.f), fmaxf(m0[2]+b2v[2],0.f), fmaxf(m0[3]+b2v[3],0.f));
      *(u32*)(d2b + (16 + j_in) * 136 + c0) =
        pk4(fmaxf(m1[0]+b2v[0],0.f), fmaxf(m1[1]+b2v[1],0.f), fmaxf(m1[2]+b2v[2],0.f), fmaxf(m1[3]+b2v[3],0.f));
    }
    __syncthreads(); // B2: h0 new + d2b ready

    // ---- P3: GRU1 + dm + yb staging ----
    {
      f32x4 aR[2] = {{0,0,0,0},{0,0,0,0}};
      f32x4 aZ[2] = {{0,0,0,0},{0,0,0,0}};
      f32x4 aN[2] = {{0,0,0,0},{0,0,0,0}};
      f32x4 aG[2] = {{0,0,0,0},{0,0,0,0}};
      const u8* pG0a = h0n + j_in * 136 + kq * 8;
      const u8* pG0b = h0n + (16 + j_in) * 136 + kq * 8;
#pragma unroll
      for (int kt = 0; kt < 8; ++kt) {
        i64 bb0, bb1;
        if (kt < 4) { bb0 = *(const i64*)(pG0a + kt * 32);        bb1 = *(const i64*)(pG0b + kt * 32); }
        else        { bb0 = *(const i64*)(pH1a + (kt - 4) * 32);  bb1 = *(const i64*)(pH1b + (kt - 4) * 32); }
        MFMA_F8(aR[0], w1r[kt], bb0); MFMA_F8(aR[1], w1r[kt], bb1);
        MFMA_F8(aZ[0], w1z[kt], bb0); MFMA_F8(aZ[1], w1z[kt], bb1);
        if (kt < 4) { MFMA_F8(aN[0], w1n[kt], bb0); MFMA_F8(aN[1], w1n[kt], bb1); }
        else        { MFMA_F8(aG[0], wn1[kt - 4], bb0); MFMA_F8(aG[1], wn1[kt - 4], bb1); }
      }
      // dm partials (reads d2b) while GRU1 MFMAs drain
      {
        int row = tid >> 4, c = (tid >> 3) & 1, part = tid & 7;
        const u8* dp = d2b + row * 136 + part * 16;
        const float* wmr = bias + 1280 + c * 128 + part * 16;
        float s = 0.f;
#pragma unroll
        for (int q = 0; q < 4; ++q) {
          u32 w = *(const u32*)(dp + q * 4);
          s += wmr[q * 4 + 0] * __builtin_amdgcn_cvt_f32_fp8((int)w, 0);
          s += wmr[q * 4 + 1] * __builtin_amdgcn_cvt_f32_fp8((int)w, 1);
          s += wmr[q * 4 + 2] * __builtin_amdgcn_cvt_f32_fp8((int)w, 2);
          s += wmr[q * 4 + 3] * __builtin_amdgcn_cvt_f32_fp8((int)w, 3);
        }
        s += __shfl_xor(s, 1); s += __shfl_xor(s, 2); s += __shfl_xor(s, 4);
        if (part == 0) dmv[t][row][c] = s;
      }
      f32x4 brv = *(const f32x4*)(bias + 512 + c0);
      f32x4 bzv = *(const f32x4*)(bias + 640 + c0);
      f32x4 biv = *(const f32x4*)(bias + 768 + c0);
      f32x4 bhv = *(const f32x4*)(bias + 896 + c0);
#pragma unroll
      for (int nt = 0; nt < 2; ++nt)
#pragma unroll
        for (int i = 0; i < 4; ++i) {
          float rv = sigf(aR[nt][i] + brv[i]);
          float zv = sigf(aZ[nt][i] + bzv[i]);
          float nv = tanh_fast(aN[nt][i] + biv[i] + rv * (aG[nt][i] + bhv[i]));
          hv1[nt][i] = (1.f - zv) * nv + zv * hv1[nt][i];
        }
#pragma unroll
      for (int nt = 0; nt < 2; ++nt)
        *(u32*)(h1n + (nt * 16 + j_in) * 136 + c0) = pk4(hv1[nt][0], hv1[nt][1], hv1[nt][2], hv1[nt][3]);
    }
    // yb staging for t+1
#pragma unroll
    for (int q = 0; q < 2; ++q) {
      int idx = tid + q * 512;
      if (idx < 768) {
        int i = idx / 24, k4 = idx - i * 24;
        *(u32*)(ybn + i * 104 + k4 * 4) = pk4(yst[q][0], yst[q][1], yst[q][2], yst[q][3]);
      }
    }
    __syncthreads(); // B3
  }

  // ---- error phase (post-loop, fully parallel) ----
  float accL = 0.f, accEp = 0.f, accEv = 0.f;
  const float bm0 = bmg[g * 2], bm1 = bmg[g * 2 + 1];
  for (int idx = tid; idx < 1536; idx += 512) {
    int t = idx >> 5, row = idx & 31;
    const float* sr = states + ((size_t)(t * 256 + b0 + row)) * 92 + aAg * 4;
    const float* sn = sr + 256 * 92;
    float dx = dmv[t][row][0] + bm0 - sn[2];
    float dy = dmv[t][row][1] + bm1 - sn[3];
    float e = sqrtf(dx * dx + dy * dy);
    accL += e;
    if (t >= 12) {
      accEv += e;
      float ex = sr[0] + 0.1f * sr[2] - sn[0];
      float ey = sr[1] + 0.1f * sr[3] - sn[1];
      accEp += sqrtf(ex * ex + ey * ey);
    }
  }
#pragma unroll
  for (int k = 1; k < 64; k <<= 1) {
    accL  += __shfl_xor(accL, k);
    accEp += __shfl_xor(accEp, k);
    accEv += __shfl_xor(accEv, k);
  }
  if (ln == 0) { red[wid][0] = accL; red[wid][1] = accEp; red[wid][2] = accEv; }
  __syncthreads();
  if (tid < 3) {
    float s = 0.f;
    for (int i = 0; i < 8; ++i) s += red[i][tid];
    atomicAdd(&wsf[tid], s);
  }
}

__global__ void fin_kernel(const float* __restrict__ wacc, float* __restrict__ out) {
  if (threadIdx.x == 0 && blockIdx.x == 0) {
    out[0] = wacc[0] / 1104.f;
    out[1] = wacc[1] / 828.f;
    out[2] = wacc[2] / 828.f;
  }
}

extern "C" void kernel_launch(void* const* d_in, const int* in_sizes, int n_in,
                              void* d_out, int out_size, void* d_ws, size_t ws_size,
                              hipStream_t stream) {
  const float* states = (const float*)d_in[0];
  const float* Wih0 = (const float*)d_in[1];
  const float* Whh0 = (const float*)d_in[2];
  const float* bih0 = (const float*)d_in[3];
  const float* bhh0 = (const float*)d_in[4];
  const float* Wih1 = (const float*)d_in[5];
  const float* Whh1 = (const float*)d_in[6];
  const float* bih1 = (const float*)d_in[7];
  const float* bhh1 = (const float*)d_in[8];
  const float* W1   = (const float*)d_in[9];
  const float* b1   = (const float*)d_in[10];
  const float* W2   = (const float*)d_in[11];
  const float* b2   = (const float*)d_in[12];
  const float* Wm   = (const float*)d_in[13];
  const float* bm   = (const float*)d_in[14];

  float* wsf = (float*)d_ws;
  u8* wb = (u8*)d_ws + WB_BYTE_OFF;

  int prep_blocks = (TOTAL + 255) / 256;
  prep_kernel<<<prep_blocks, 256, 0, stream>>>(Wih0, Whh0, bih0, bhh0,
                                               Wih1, Whh1, bih1, bhh1,
                                               W1, W2, wb, wsf);
  rnn_kernel<<<184, 512, 0, stream>>>(states, wb, wsf, b1, b2, Wm, bm);
  fin_kernel<<<1, 64, 0, stream>>>(wsf, (float*)d_out);
}